// Round 18
// baseline (562.759 us; speedup 1.0000x reference)
//
#include <hip/hip_runtime.h>
#include <hip/hip_bf16.h>
#include <cstddef>

// ---------------- dims ----------------
#define S_DIM 512
#define B_DIM 256
#define PD 512
#define OD 256
#define DD 512
#define ID_DIM 1024
#define V_DIM 1000
#define EMB 64
#define IN0_PAD 96   // 1+EMB=65 padded to 96 (multiple of 32 for MFMA K)

typedef short short8 __attribute__((ext_vector_type(8)));
typedef float f32x4 __attribute__((ext_vector_type(4)));
typedef unsigned short us4 __attribute__((ext_vector_type(4)));
typedef unsigned short us8 __attribute__((ext_vector_type(8)));

// ---------------- helpers ----------------
__device__ __forceinline__ float fast_exp(float x) { return __expf(x); }
__device__ __forceinline__ float fast_tanh(float x) {
    float e = __expf(2.0f * x);
    return 1.0f - 2.0f * __builtin_amdgcn_rcpf(e + 1.0f);
}
__device__ __forceinline__ float fast_sigm(float x) {
    return __builtin_amdgcn_rcpf(1.0f + __expf(-x));
}

__device__ __forceinline__ unsigned short f2bfu(float f) {
    __hip_bfloat16 h = __float2bfloat16(f);
    return *reinterpret_cast<unsigned short*>(&h);
}
__device__ __forceinline__ float bf2f(unsigned short u) {
    unsigned int x = ((unsigned int)u) << 16;
    return __builtin_bit_cast(float, x);
}

__device__ __forceinline__ float wred_max(float v) {
#pragma unroll
    for (int o = 32; o; o >>= 1) v = fmaxf(v, __shfl_xor(v, o));
    return v;
}
__device__ __forceinline__ float wred_sum(float v) {
#pragma unroll
    for (int o = 32; o; o >>= 1) v += __shfl_xor(v, o);
    return v;
}

// ---------------- build x (padded) ----------------
__global__ __launch_bounds__(128) void build_x_kernel(
    const float* __restrict__ p_ts, const int* __restrict__ p_cat,
    const float* __restrict__ emb, float* __restrict__ x)
{
    int b = blockIdx.x, t = threadIdx.x;
    if (t < IN0_PAD) {
        float val = 0.f;
        if (t == 0) val = p_ts[b];
        else if (t < 65) val = emb[(size_t)p_cat[b] * EMB + (t - 1)];
        x[(size_t)b * IN0_PAD + t] = val;
    }
}

// ---------------- ||v||_1 for the 3 attention v vectors ----------------
__global__ __launch_bounds__(512) void vnorm_kernel(
    const float* __restrict__ pv, const float* __restrict__ av,
    const float* __restrict__ iv, float* __restrict__ Mout)
{
    const float* v = blockIdx.x == 0 ? pv : (blockIdx.x == 1 ? av : iv);
    __shared__ float tmp[8];
    const int tid = threadIdx.x;
    float x = fabsf(v[tid]);
    x = wred_sum(x);
    if ((tid & 63) == 0) tmp[tid >> 6] = x;
    __syncthreads();
    if (tid == 0) {
        float s = 0.f;
#pragma unroll
        for (int i = 0; i < 8; ++i) s += tmp[i];
        Mout[blockIdx.x] = s;
    }
}

// ---------------- concat 4 dec biases in one launch ----------------
__global__ __launch_bounds__(256) void concat_bias(
    const float* __restrict__ pb, const float* __restrict__ ab,
    const float* __restrict__ ib, const float* __restrict__ cb,
    float* __restrict__ dst)
{
    const int t = blockIdx.x * 256 + threadIdx.x;  // 0..2047
    const float* src = (t < 512) ? pb : (t < 1024 ? ab : (t < 1536 ? ib : cb));
    dst[t] = src[t & 511];
}

// ---------------- swizzle pW enc-half into MFMA fragment order ----------------
__global__ __launch_bounds__(256) void swizzle_wp(
    const float* __restrict__ pW, unsigned short* __restrict__ dst)
{
    const int o = blockIdx.x * 256 + threadIdx.x;
    const int e    = o & 7;
    const int lane = (o >> 3) & 63;
    const int mi   = (o >> 9) & 3;
    const int ks   = (o >> 11) & 15;
    const int w    = o >> 15;
    const int row = (w << 6) + (mi << 4) + (lane & 15);
    const int col = (ks << 5) + ((lane >> 4) << 3) + e;
    dst[o] = f2bfu(pW[(size_t)row * 1024 + 512 + col]);
}

// ---------------- fused multi-job f32 -> bf16 weight convert ----------------
struct ConvJob {
    const float* src; unsigned short* dst;
    int ld, col0, ncols, srccols, bstart, total;
};
struct ConvJobs { ConvJob j[17]; int nj; };

__global__ __launch_bounds__(256) void conv_all(ConvJobs jobs)
{
    const int blk = blockIdx.x;
    int ji = 0;
#pragma unroll
    for (int k = 1; k < 17; ++k)
        if (k < jobs.nj && jobs.j[k].bstart <= blk) ji = k;
    const ConvJob jb = jobs.j[ji];
    const int idx = (blk - jb.bstart) * 256 + threadIdx.x;
    if (idx >= jb.total) return;
    const int r = idx / jb.ncols, c = idx - r * jb.ncols;
    const float v = (c < jb.srccols) ? jb.src[(size_t)r * jb.ld + jb.col0 + c] : 0.f;
    jb.dst[idx] = f2bfu(v);
}

// ---------------- bf16 MFMA GEMM: C = act(A1@W1^T [+ A2@W2^T] + b1 [+ b2]) ----------------
__global__ __launch_bounds__(256) void gemm_mfma(
    const float* __restrict__ A1, int lda1,
    const unsigned short* __restrict__ W1, int ldw1, int K1,
    const float* __restrict__ A2, int lda2,
    const unsigned short* __restrict__ W2, int ldw2, int K2,
    const float* __restrict__ bias1, const float* __restrict__ bias2,
    float* __restrict__ C, int ldc, int N, int relu)
{
    __shared__ alignas(16) unsigned short As[64][40];
    __shared__ alignas(16) unsigned short Ws[64][40];
    const int tid = threadIdx.x;
    const int l = tid & 63, wvid = tid >> 6;
    const int wx = wvid & 1, wy = wvid >> 1;
    const int bm = blockIdx.y << 6, bn = blockIdx.x << 6;
    const int sr = tid >> 2, sc = (tid & 3) << 3;
    const int lk = (l >> 4) << 3;
    f32x4 acc[2][2] = {};

    for (int pass = 0; pass < 2; ++pass) {
        const float* A = pass ? A2 : A1;
        if (!A) continue;
        const unsigned short* W = pass ? W2 : W1;
        const int lda = pass ? lda2 : lda1;
        const int ldw = pass ? ldw2 : ldw1;
        const int K = pass ? K2 : K1;
        for (int k0 = 0; k0 < K; k0 += 32) {
            const float* ap = A + (size_t)(bm + sr) * lda + k0 + sc;
            float4 a0 = *reinterpret_cast<const float4*>(ap);
            float4 a1 = *reinterpret_cast<const float4*>(ap + 4);
            us8 pk = { f2bfu(a0.x), f2bfu(a0.y), f2bfu(a0.z), f2bfu(a0.w),
                       f2bfu(a1.x), f2bfu(a1.y), f2bfu(a1.z), f2bfu(a1.w) };
            *reinterpret_cast<us8*>(&As[sr][sc]) = pk;
            const int wr = bn + sr;
            short8 wvv = { 0, 0, 0, 0, 0, 0, 0, 0 };
            if (wr < N) wvv = *reinterpret_cast<const short8*>(W + (size_t)wr * ldw + k0 + sc);
            *reinterpret_cast<short8*>(&Ws[sr][sc]) = wvv;
            __syncthreads();
            short8 wf[2], af[2];
#pragma unroll
            for (int i = 0; i < 2; ++i) {
                wf[i] = *reinterpret_cast<const short8*>(&Ws[(wx << 5) + (i << 4) + (l & 15)][lk]);
                af[i] = *reinterpret_cast<const short8*>(&As[(wy << 5) + (i << 4) + (l & 15)][lk]);
            }
#pragma unroll
            for (int wi = 0; wi < 2; ++wi)
#pragma unroll
                for (int ai = 0; ai < 2; ++ai)
                    acc[wi][ai] = __builtin_amdgcn_mfma_f32_16x16x32_bf16(wf[wi], af[ai], acc[wi][ai], 0, 0, 0);
            __syncthreads();
        }
    }

#pragma unroll
    for (int wi = 0; wi < 2; ++wi) {
#pragma unroll
        for (int ai = 0; ai < 2; ++ai) {
            const int n0 = bn + (wx << 5) + (wi << 4) + ((l >> 4) << 2);
            const int m  = bm + (wy << 5) + (ai << 4) + (l & 15);
            if (n0 >= N) continue;
            f32x4 a = acc[wi][ai];
            float4 r = make_float4(a.x, a.y, a.z, a.w);
            if (bias1) {
                float4 b = *reinterpret_cast<const float4*>(bias1 + n0);
                r.x += b.x; r.y += b.y; r.z += b.z; r.w += b.w;
            }
            if (bias2) {
                float4 b = *reinterpret_cast<const float4*>(bias2 + n0);
                r.x += b.x; r.y += b.y; r.z += b.z; r.w += b.w;
            }
            if (relu) {
                r.x = fmaxf(r.x, 0.f); r.y = fmaxf(r.y, 0.f);
                r.z = fmaxf(r.z, 0.f); r.w = fmaxf(r.w, 0.f);
            }
            *reinterpret_cast<float4*>(&C[(size_t)m * ldc + n0]) = r;
        }
    }
}

// ---------------- ALL THREE attentions in ONE launch ----------------
// grid (B, 4, 3): z=0 -> p (E=512, swizzled-Wb LDS-stream path, r13 structure);
// z=1 -> a, z=2 -> i (E=256, Wb-in-registers path, r15 structure).
// Rationale (r18): p (185us, 46% occ) and a/i (196us, 23% occ) are both
// latency-bound AND independent, yet stream order serialized them (381us).
// One launch lets p-blocks' stall cycles be filled by a/i waves and vice
// versa, and deletes the inter-kernel drain. Unified regalloc = max(paths)
// = ~128 VGPR; p still fits 2 blocks/CU (4 waves/SIMD x 128 = 512 regs).
// LDS unioned: 33792 B (wreg's need) >= p's 33280 B -> 2 blocks/CU both.
__global__ __launch_bounds__(512, 2) void attn_all(
    const float* __restrict__ p_enc_, const unsigned short* __restrict__ Wsw_p,
    const float* __restrict__ enc_a, const float* __restrict__ enc_i,
    const unsigned short* __restrict__ Wb_a, const unsigned short* __restrict__ Wb_i,
    const float* __restrict__ decp_all, int ldd,
    const float* __restrict__ pv, const float* __restrict__ va, const float* __restrict__ vi,
    const float* __restrict__ Mv,
    float* __restrict__ part_p_, float* __restrict__ part_a_, float* __restrict__ part_i_,
    float* __restrict__ lsum_p_, float* __restrict__ lsum_a_, float* __restrict__ lsum_i_)
{
    // union'd LDS: wreg path needs 2*32*264 ushorts = 33792 B >= p path 32*520*2 = 33280 B
    __shared__ alignas(16) unsigned short encS[2 * 32 * 264];
    __shared__ float red[32][9];
    __shared__ float wexp[32];

    const int tid = threadIdx.x;
    const int w = tid >> 6, l = tid & 63;
    const int b = blockIdx.x, z = blockIdx.y;
    const int zone = blockIdx.z;
    const int s0 = z << 7;
    const int srow = tid >> 4;
    const int sq = tid & 15;
    const int lk = (l >> 4) << 3;
    const int nb0 = (w << 6) + ((l >> 4) << 2);

    if (zone == 0) {
        // ================= p path (E=512, swizzled Wb stream) =================
        constexpr int E = 512;
        constexpr int LROW = E + 8;          // 520
        constexpr int NT = 4, NF4 = 8, NKS = 16;
        unsigned short (*encL)[LROW] = reinterpret_cast<unsigned short (*)[LROW]>(encS);
        const float M = Mv[0];
        const float* encb = p_enc_ + (size_t)b * E;
        const unsigned short* wswz = Wsw_p + ((size_t)w * NKS * 4 * 512) + (l << 3);
        const float* drow = decp_all + (size_t)b * ldd + nb0;

        float ctx_acc = 0.f, l_acc = 0.f;

#pragma unroll 1
        for (int t = 0; t < NT; ++t) {
            {
                const float* rowp = encb + (size_t)(s0 + (t << 5) + srow) * B_DIM * E;
                float4 r[NF4];
#pragma unroll
                for (int j = 0; j < NF4; ++j)
                    r[j] = *reinterpret_cast<const float4*>(rowp + ((sq + (j << 4)) << 2));
#pragma unroll
                for (int j = 0; j < NF4; ++j) {
                    us4 pk = { f2bfu(r[j].x), f2bfu(r[j].y), f2bfu(r[j].z), f2bfu(r[j].w) };
                    *reinterpret_cast<us4*>(&encL[srow][(sq + (j << 4)) << 2]) = pk;
                }
            }
            __syncthreads();

            f32x4 acc[4][2] = {};
#pragma unroll 4
            for (int ks = 0; ks < NKS; ++ks) {
                short8 bfr[2];
#pragma unroll
                for (int ni = 0; ni < 2; ++ni)
                    bfr[ni] = *reinterpret_cast<const short8*>(
                        &encL[(ni << 4) + (l & 15)][(ks << 5) + lk]);
#pragma unroll
                for (int mi = 0; mi < 4; ++mi) {
                    short8 afr = *reinterpret_cast<const short8*>(wswz + (((ks << 2) + mi) << 9));
#pragma unroll
                    for (int ni = 0; ni < 2; ++ni)
                        acc[mi][ni] = __builtin_amdgcn_mfma_f32_16x16x32_bf16(afr, bfr[ni], acc[mi][ni], 0, 0, 0);
                }
            }

            float p0 = 0.f, p1 = 0.f;
#pragma unroll
            for (int mi = 0; mi < 4; ++mi) {
                float4 d   = *reinterpret_cast<const float4*>(drow + (mi << 4));
                float4 vvm = *reinterpret_cast<const float4*>(pv + nb0 + (mi << 4));
                f32x4 a0 = acc[mi][0];
                p0 += fast_tanh(a0.x + d.x) * vvm.x;
                p0 += fast_tanh(a0.y + d.y) * vvm.y;
                p0 += fast_tanh(a0.z + d.z) * vvm.z;
                p0 += fast_tanh(a0.w + d.w) * vvm.w;
                f32x4 a1 = acc[mi][1];
                p1 += fast_tanh(a1.x + d.x) * vvm.x;
                p1 += fast_tanh(a1.y + d.y) * vvm.y;
                p1 += fast_tanh(a1.z + d.z) * vvm.z;
                p1 += fast_tanh(a1.w + d.w) * vvm.w;
            }
            p0 += __shfl_xor(p0, 16); p0 += __shfl_xor(p0, 32);
            p1 += __shfl_xor(p1, 16); p1 += __shfl_xor(p1, 32);
            if (l < 16) { red[l][w] = p0; red[16 + l][w] = p1; }
            __syncthreads();

            if (tid < 32) {
                float ssum = 0.f;
#pragma unroll
                for (int ww = 0; ww < 8; ++ww) ssum += red[tid][ww];
                float wsv = fast_exp(ssum - M);
                wexp[tid] = wsv;
                float t2 = wsv;
                t2 += __shfl_xor(t2, 16); t2 += __shfl_xor(t2, 8);
                t2 += __shfl_xor(t2, 4);  t2 += __shfl_xor(t2, 2);
                t2 += __shfl_xor(t2, 1);
                if (tid == 0) l_acc += t2;
            }
            __syncthreads();

            if (tid < E) {
                float a = 0.f;
#pragma unroll 8
                for (int s = 0; s < 32; ++s)
                    a += wexp[s] * bf2f(encL[s][tid]);
                ctx_acc += a;
            }
            __syncthreads();
        }

        if (tid < E)
            part_p_[((size_t)z * B_DIM + b) * E + tid] = ctx_acc;
        if (tid == 0)
            lsum_p_[z * B_DIM + b] = l_acc;
    } else {
        // ================= a/i path (E=256, Wb in registers) =================
        constexpr int E = 256;
        constexpr int LROW = E + 8;          // 264
        constexpr int NT = 4, NF4 = 4;
        unsigned short (*encL)[32][LROW] = reinterpret_cast<unsigned short (*)[32][LROW]>(encS);
        const int sel = zone - 1;            // 0 = a, 1 = i
        const float* enc  = sel ? enc_i  : enc_a;
        const unsigned short* Wb = sel ? Wb_i : Wb_a;
        const float* decp = decp_all + (sel ? 1024 : 512);
        const float* v    = sel ? vi : va;
        const float M     = sel ? Mv[2] : Mv[1];
        float* ctx_part   = sel ? part_i_ : part_a_;
        float* lsum       = sel ? lsum_i_ : lsum_a_;

        const float* encb = enc + (size_t)b * E;
        const unsigned short* wbase = Wb + (size_t)((w << 6) + (l & 15)) * E + lk;
        const float* drow = decp + (size_t)b * ldd + nb0;

        short8 afrA[4][4], afrB[4][4];
#pragma unroll
        for (int mi = 0; mi < 4; ++mi) {
#pragma unroll
            for (int j = 0; j < 4; ++j) {
                afrA[mi][j] = *reinterpret_cast<const short8*>(wbase + (size_t)(mi << 4) * E + (j << 5));
                afrB[mi][j] = *reinterpret_cast<const short8*>(wbase + (size_t)(mi << 4) * E + ((j + 4) << 5));
            }
        }

        {
            const float* rowp = encb + (size_t)(s0 + srow) * B_DIM * E;
            float4 r[NF4];
#pragma unroll
            for (int j = 0; j < NF4; ++j)
                r[j] = *reinterpret_cast<const float4*>(rowp + ((sq + (j << 4)) << 2));
#pragma unroll
            for (int j = 0; j < NF4; ++j) {
                us4 pk = { f2bfu(r[j].x), f2bfu(r[j].y), f2bfu(r[j].z), f2bfu(r[j].w) };
                *reinterpret_cast<us4*>(&encL[0][srow][(sq + (j << 4)) << 2]) = pk;
            }
        }
        __syncthreads();

        float ctx_acc = 0.f, l_acc = 0.f;
        int cur = 0;

#pragma unroll 1
        for (int t = 0; t < NT; ++t) {
            float4 rn[NF4];
            const bool more = (t + 1) < NT;
            if (more) {
                const float* rowp = encb + (size_t)(s0 + ((t + 1) << 5) + srow) * B_DIM * E;
#pragma unroll
                for (int j = 0; j < NF4; ++j)
                    rn[j] = *reinterpret_cast<const float4*>(rowp + ((sq + (j << 4)) << 2));
            }

            f32x4 acc[4][2] = {};
#pragma unroll
            for (int j = 0; j < 4; ++j) {
                short8 b0 = *reinterpret_cast<const short8*>(&encL[cur][(l & 15)][(j << 5) + lk]);
                short8 b1 = *reinterpret_cast<const short8*>(&encL[cur][16 + (l & 15)][(j << 5) + lk]);
#pragma unroll
                for (int mi = 0; mi < 4; ++mi) {
                    acc[mi][0] = __builtin_amdgcn_mfma_f32_16x16x32_bf16(afrA[mi][j], b0, acc[mi][0], 0, 0, 0);
                    acc[mi][1] = __builtin_amdgcn_mfma_f32_16x16x32_bf16(afrA[mi][j], b1, acc[mi][1], 0, 0, 0);
                }
            }
#pragma unroll
            for (int j = 0; j < 4; ++j) {
                short8 b0 = *reinterpret_cast<const short8*>(&encL[cur][(l & 15)][((j + 4) << 5) + lk]);
                short8 b1 = *reinterpret_cast<const short8*>(&encL[cur][16 + (l & 15)][((j + 4) << 5) + lk]);
#pragma unroll
                for (int mi = 0; mi < 4; ++mi) {
                    acc[mi][0] = __builtin_amdgcn_mfma_f32_16x16x32_bf16(afrB[mi][j], b0, acc[mi][0], 0, 0, 0);
                    acc[mi][1] = __builtin_amdgcn_mfma_f32_16x16x32_bf16(afrB[mi][j], b1, acc[mi][1], 0, 0, 0);
                }
            }

            float p0 = 0.f, p1 = 0.f;
#pragma unroll
            for (int mi = 0; mi < 4; ++mi) {
                float4 d   = *reinterpret_cast<const float4*>(drow + (mi << 4));
                float4 vvm = *reinterpret_cast<const float4*>(v + nb0 + (mi << 4));
                f32x4 a0 = acc[mi][0];
                p0 += fast_tanh(a0.x + d.x) * vvm.x;
                p0 += fast_tanh(a0.y + d.y) * vvm.y;
                p0 += fast_tanh(a0.z + d.z) * vvm.z;
                p0 += fast_tanh(a0.w + d.w) * vvm.w;
                f32x4 a1 = acc[mi][1];
                p1 += fast_tanh(a1.x + d.x) * vvm.x;
                p1 += fast_tanh(a1.y + d.y) * vvm.y;
                p1 += fast_tanh(a1.z + d.z) * vvm.z;
                p1 += fast_tanh(a1.w + d.w) * vvm.w;
            }
            p0 += __shfl_xor(p0, 16); p0 += __shfl_xor(p0, 32);
            p1 += __shfl_xor(p1, 16); p1 += __shfl_xor(p1, 32);
            if (l < 16) { red[l][w] = p0; red[16 + l][w] = p1; }
            __syncthreads();

            if (tid < 32) {
                float ssum = 0.f;
#pragma unroll
                for (int ww = 0; ww < 8; ++ww) ssum += red[tid][ww];
                float wsv = fast_exp(ssum - M);
                wexp[tid] = wsv;
                float t2 = wsv;
                t2 += __shfl_xor(t2, 16); t2 += __shfl_xor(t2, 8);
                t2 += __shfl_xor(t2, 4);  t2 += __shfl_xor(t2, 2);
                t2 += __shfl_xor(t2, 1);
                if (tid == 0) l_acc += t2;
            }
            __syncthreads();

            if (tid < E) {
                float a = 0.f;
#pragma unroll 8
                for (int s = 0; s < 32; ++s)
                    a += wexp[s] * bf2f(encL[cur][s][tid]);
                ctx_acc += a;
            }

            if (more) {
#pragma unroll
                for (int j = 0; j < NF4; ++j) {
                    us4 pk = { f2bfu(rn[j].x), f2bfu(rn[j].y), f2bfu(rn[j].z), f2bfu(rn[j].w) };
                    *reinterpret_cast<us4*>(&encL[cur ^ 1][srow][(sq + (j << 4)) << 2]) = pk;
                }
            }
            __syncthreads();
            cur ^= 1;
        }

        if (tid < E)
            ctx_part[((size_t)z * B_DIM + b) * E + tid] = ctx_acc;
        if (tid == 0)
            lsum[z * B_DIM + b] = l_acc;
    }
}

// ---------------- ONE-launch combine for all three attentions ----------------
__global__ __launch_bounds__(256) void ctx_combine3(
    const float* __restrict__ part_p, const float* __restrict__ lsum_p,
    const float* __restrict__ part_a, const float* __restrict__ lsum_a,
    const float* __restrict__ part_i, const float* __restrict__ lsum_i,
    float* __restrict__ p_ctx, float* __restrict__ comb_a, float* __restrict__ comb_i)
{
    const int b = blockIdx.x, y = blockIdx.y;
    const float* part; const float* lsum; float* out; int E, e;
    if (y < 2)      { part = part_p; lsum = lsum_p; out = p_ctx;  E = 512; e = (y << 8) + threadIdx.x; }
    else if (y == 2){ part = part_a; lsum = lsum_a; out = comb_a; E = 256; e = threadIdx.x; }
    else            { part = part_i; lsum = lsum_i; out = comb_i; E = 256; e = threadIdx.x; }
    const float ls = lsum[b] + lsum[B_DIM + b] + lsum[2 * B_DIM + b] + lsum[3 * B_DIM + b];
    const size_t BE = (size_t)B_DIM * E;
    const size_t idx = (size_t)b * E + e;
    const float s = part[idx] + part[BE + idx] + part[2 * BE + idx] + part[3 * BE + idx];
    out[idx] = s * __builtin_amdgcn_rcpf(ls);
}

// ---------------- MFMA attention score (combiner only, Sdim=3) ----------------
template<int E>
__global__ __launch_bounds__(512, 4) void attn_score_mfma(
    const float* __restrict__ enc,
    const unsigned short* __restrict__ Wb,
    const float* __restrict__ decp, int ldd,
    const float* __restrict__ v,
    float* __restrict__ score, int Sdim)
{
    __shared__ alignas(16) unsigned short Al[64][E + 8];
    __shared__ float red[64][9];
    const int tid = threadIdx.x;
    const int w = tid >> 6, l = tid & 63;
    const int m0 = blockIdx.x << 6;
    constexpr int NKS = E >> 5;

    const int srow = tid >> 3;
    const int scol = (tid & 7) << 3;
    {
        const float* srcp = enc + (size_t)(m0 + srow) * E + scol;
        float4 a0 = *reinterpret_cast<const float4*>(srcp);
        float4 a1 = *reinterpret_cast<const float4*>(srcp + 4);
        us8 pk = { f2bfu(a0.x), f2bfu(a0.y), f2bfu(a0.z), f2bfu(a0.w),
                   f2bfu(a1.x), f2bfu(a1.y), f2bfu(a1.z), f2bfu(a1.w) };
        *reinterpret_cast<us8*>(&Al[srow][scol]) = pk;
    }
    __syncthreads();

    f32x4 acc[4][4] = {};
    const int lk = (l >> 4) << 3;
    const unsigned short* wbase = Wb + (size_t)((w << 6) + (l & 15)) * E + lk;

#pragma unroll 2
    for (int ks = 0; ks < NKS; ++ks) {
        short8 bfr[4];
#pragma unroll
        for (int ni = 0; ni < 4; ++ni)
            bfr[ni] = *reinterpret_cast<const short8*>(&Al[(ni << 4) + (l & 15)][(ks << 5) + lk]);
#pragma unroll
        for (int mi = 0; mi < 4; ++mi) {
            short8 afr = *reinterpret_cast<const short8*>(wbase + (size_t)(mi << 4) * E + (ks << 5));
#pragma unroll
            for (int ni = 0; ni < 4; ++ni)
                acc[mi][ni] = __builtin_amdgcn_mfma_f32_16x16x32_bf16(afr, bfr[ni], acc[mi][ni], 0, 0, 0);
        }
    }

    const int nb0 = (w << 6) + ((l >> 4) << 2);
#pragma unroll
    for (int ni = 0; ni < 4; ++ni) {
        const int ml = (ni << 4) + (l & 15);
        const int b = (m0 + ml) & (B_DIM - 1);
        const float* drow = decp + (size_t)b * ldd + nb0;
        float p = 0.f;
#pragma unroll
        for (int mi = 0; mi < 4; ++mi) {
            float4 d = *reinterpret_cast<const float4*>(drow + (mi << 4));
            float4 vvm = *reinterpret_cast<const float4*>(v + nb0 + (mi << 4));
            f32x4 a = acc[mi][ni];
            p += fast_tanh(a.x + d.x) * vvm.x;
            p += fast_tanh(a.y + d.y) * vvm.y;
            p += fast_tanh(a.z + d.z) * vvm.z;
            p += fast_tanh(a.w + d.w) * vvm.w;
        }
        p += __shfl_xor(p, 16);
        p += __shfl_xor(p, 32);
        if (l < 16) red[(ni << 4) + l][w] = p;
    }
    __syncthreads();
    if (tid < 64) {
        float ssum = 0.f;
#pragma unroll
        for (int ww = 0; ww < 8; ++ww) ssum += red[tid][ww];
        const int m = m0 + tid;
        score[(size_t)(m & (B_DIM - 1)) * Sdim + (m >> 8)] = ssum;
    }
}

// ---------------- softmax rows in place: x [B, Sdim] ----------------
__global__ __launch_bounds__(256) void softmax_rows(float* __restrict__ x, int Sdim)
{
    const int b = blockIdx.x, tid = threadIdx.x;
    const int lane = tid & 63, wid = tid >> 6;
    float* row = x + (size_t)b * Sdim;
    __shared__ float tmp[4];
    float m = -3.4e38f;
    for (int s = tid; s < Sdim; s += 256) m = fmaxf(m, row[s]);
    m = wred_max(m);
    if (lane == 0) tmp[wid] = m;
    __syncthreads();
    m = fmaxf(fmaxf(tmp[0], tmp[1]), fmaxf(tmp[2], tmp[3]));
    __syncthreads();
    float sum = 0.f;
    for (int s = tid; s < Sdim; s += 256) { float e = fast_exp(row[s] - m); row[s] = e; sum += e; }
    sum = wred_sum(sum);
    if (lane == 0) tmp[wid] = sum;
    __syncthreads();
    sum = tmp[0] + tmp[1] + tmp[2] + tmp[3];
    const float inv = 1.0f / sum;
    for (int s = tid; s < Sdim; s += 256) row[s] *= inv;
}

// ---------------- small weighted context (combiner, Sdim=3) ----------------
__global__ __launch_bounds__(256) void ctx_kernel(
    const float* __restrict__ w, const float* __restrict__ enc,
    float* __restrict__ out, int Sdim, int E)
{
    const int b = blockIdx.x;
    const int e = blockIdx.y * 256 + threadIdx.x;
    if (e >= E) return;
    const float* wr = w + (size_t)b * Sdim;
    float acc = 0.f;
    for (int s = 0; s < Sdim; ++s)
        acc += wr[s] * enc[((size_t)s * B_DIM + b) * E + e];
    out[(size_t)b * E + e] = acc;
}

// ---------------- LSTM pointwise ----------------
__global__ __launch_bounds__(256) void lstm_pw(
    const float* __restrict__ g, const float* __restrict__ cprev,
    float* __restrict__ h_out, float* __restrict__ c_out, float* __restrict__ h_copy)
{
    const int idx = blockIdx.x * 256 + threadIdx.x;
    const int b = idx >> 9, d = idx & 511;
    const float* gr = g + (size_t)b * 2048;
    const float ig = fast_sigm(gr[d]);
    const float fg = fast_sigm(gr[512 + d]);
    const float gg = fast_tanh(gr[1024 + d]);
    const float og = fast_sigm(gr[1536 + d]);
    const float c2 = fg * cprev[idx] + ig * gg;
    const float h2 = og * fast_tanh(c2);
    h_out[idx] = h2; c_out[idx] = c2; h_copy[idx] = h2;
}

// ---------------- ts head ----------------
__global__ __launch_bounds__(64) void ts_kernel(
    const float* __restrict__ h2, const float* __restrict__ tgW,
    const float* __restrict__ tgb, float* __restrict__ out)
{
    const int b = blockIdx.x, t = threadIdx.x;
    float s = 0.f;
    for (int d = t; d < 512; d += 64) s += h2[(size_t)b * 512 + d] * tgW[d];
    s = wred_sum(s);
    if (t == 0) out[b] = fmaxf(s + tgb[0], 0.f);
}

// ---------------- log softmax rows ----------------
__global__ __launch_bounds__(256) void log_softmax_rows(
    const float* __restrict__ in, float* __restrict__ out, int V)
{
    const int b = blockIdx.x, tid = threadIdx.x;
    const int lane = tid & 63, wid = tid >> 6;
    const float* row = in + (size_t)b * V;
    float* orow = out + (size_t)b * V;
    __shared__ float tmp[4];
    float m = -3.4e38f;
    for (int s = tid; s < V; s += 256) m = fmaxf(m, row[s]);
    m = wred_max(m);
    if (lane == 0) tmp[wid] = m;
    __syncthreads();
    m = fmaxf(fmaxf(tmp[0], tmp[1]), fmaxf(tmp[2], tmp[3]));
    __syncthreads();
    float sum = 0.f;
    for (int s = tid; s < V; s += 256) sum += fast_exp(row[s] - m);
    sum = wred_sum(sum);
    if (lane == 0) tmp[wid] = sum;
    __syncthreads();
    sum = tmp[0] + tmp[1] + tmp[2] + tmp[3];
    const float lse = m + logf(sum);
    for (int s = tid; s < V; s += 256) orow[s] = row[s] - lse;
}

// ---------------- host ----------------
extern "C" void kernel_launch(void* const* d_in, const int* in_sizes, int n_in,
                              void* d_out, int out_size, void* d_ws, size_t ws_size,
                              hipStream_t stream)
{
    const float* p_ts   = (const float*)d_in[0];
    const int*   p_cat  = (const int*)d_in[1];
    const float* p_hn   = (const float*)d_in[2];
    const float* p_hc   = (const float*)d_in[3];
    const float* p_enc  = (const float*)d_in[4];
    const float* a_enc  = (const float*)d_in[5];
    const float* i_enc  = (const float*)d_in[6];
    const float* emb    = (const float*)d_in[7];
    const float* W_ih0  = (const float*)d_in[8];
    const float* W_hh0  = (const float*)d_in[9];
    const float* b_ih0  = (const float*)d_in[10];
    const float* b_hh0  = (const float*)d_in[11];
    const float* W_ih1  = (const float*)d_in[12];
    const float* W_hh1  = (const float*)d_in[13];
    const float* b_ih1  = (const float*)d_in[14];
    const float* b_hh1  = (const float*)d_in[15];
    const float* pW = (const float*)d_in[16]; const float* pb = (const float*)d_in[17]; const float* pv = (const float*)d_in[18];
    const float* aW = (const float*)d_in[19]; const float* ab = (const float*)d_in[20]; const float* av = (const float*)d_in[21];
    const float* iW = (const float*)d_in[22]; const float* ib = (const float*)d_in[23]; const float* iv = (const float*)d_in[24];
    const float* cW = (const float*)d_in[25]; const float* cb = (const float*)d_in[26]; const float* cv = (const float*)d_in[27];
    const float* p2o_W = (const float*)d_in[28]; const float* p2o_b = (const float*)d_in[29];
    const float* o2p_W = (const float*)d_in[30]; const float* o2p_b = (const float*)d_in[31];
    const float* out1_W = (const float*)d_in[32]; const float* out1_b = (const float*)d_in[33];
    const float* out2_W = (const float*)d_in[34]; const float* out2_b = (const float*)d_in[35];
    const float* mg_W = (const float*)d_in[36]; const float* mg_b = (const float*)d_in[37];
    const float* tg_W = (const float*)d_in[38]; const float* tg_b = (const float*)d_in[39];

    float* out = (float*)d_out;
    float* ws  = (float*)d_ws;

    // ---- output offsets (floats) ----
    float* out_ts  = out;
    float* out_cat = out + 256;
    float* out_hn0 = out + 256256;
    float* out_hn1 = out + 256256 + 131072;
    float* out_hc0 = out + 518400;
    float* out_hc1 = out + 518400 + 131072;

    // ---- workspace layout (floats) ----
    size_t off = 0;
    float* x_pad    = ws + off; off += (size_t)B_DIM * IN0_PAD;
    float* g_buf    = ws + off; off += (size_t)B_DIM * 2048;      // aliased: part_p / h_big+logits
    float* h0_ws    = ws + off; off += (size_t)B_DIM * DD;
    float* h1_ws    = ws + off; off += (size_t)B_DIM * DD;
    float* decp_all = ws + off; off += (size_t)B_DIM * 2048;
    float* score_c  = ws + off; off += 1024;
    float* Mv       = ws + off; off += 16;
    float* p_ctx    = ws + off; off += (size_t)B_DIM * PD;
    float* combined = ws + off; off += (size_t)3 * B_DIM * OD;
    float* ctx_c    = ws + off; off += (size_t)B_DIM * OD;
    float* context  = ws + off; off += (size_t)B_DIM * DD;
    float* h2_buf   = ws + off; off += (size_t)B_DIM * DD;
    float* bias_dec = ws + off; off += 2048;
    float* part_a   = ws + off; off += (size_t)4 * B_DIM * OD;
    float* part_i   = ws + off; off += (size_t)4 * B_DIM * OD;
    float* lsum_p   = ws + off; off += 1024;
    float* lsum_a   = ws + off; off += 1024;
    float* lsum_i   = ws + off; off += 1024;
    unsigned short* wb_base = (unsigned short*)(ws + off);
    size_t uo = 0;
    unsigned short* wb_ih0  = wb_base + uo; uo += (size_t)2048 * IN0_PAD;
    unsigned short* wb_hh0  = wb_base + uo; uo += (size_t)2048 * 512;
    unsigned short* wb_ih1  = wb_base + uo; uo += (size_t)2048 * 512;
    unsigned short* wb_hh1  = wb_base + uo; uo += (size_t)2048 * 512;
    unsigned short* wb_dec  = wb_base + uo; uo += (size_t)2048 * 512;
    unsigned short* wb_p    = wb_base + uo; uo += (size_t)512 * 512;   // SWIZZLED fragment order
    unsigned short* wb_a    = wb_base + uo; uo += (size_t)512 * 256;
    unsigned short* wb_i    = wb_base + uo; uo += (size_t)512 * 256;
    unsigned short* wb_c    = wb_base + uo; uo += (size_t)512 * 256;
    unsigned short* wb_p2o  = wb_base + uo; uo += (size_t)256 * 512;
    unsigned short* wb_o2p  = wb_base + uo; uo += (size_t)512 * 256;
    unsigned short* wb_out1 = wb_base + uo; uo += (size_t)1024 * 1024;
    unsigned short* wb_out2 = wb_base + uo; uo += (size_t)512 * 1024;
    unsigned short* wb_mg   = wb_base + uo; uo += (size_t)1000 * 512;
    float* part_p = g_buf;
    float* h_big  = g_buf;
    float* logits = g_buf + 262144;
    (void)ws_size; (void)n_in; (void)in_sizes; (void)out_size;

    // 0) convert weights to bf16 (one launch) + swizzled p-attn W; v norms; biases
    {
        ConvJobs cj; int nj = 0, nb = 0;
        auto add = [&](const float* src, unsigned short* dst, int ld, int col0,
                       int nrows, int ncols, int srccols) {
            ConvJob& jb = cj.j[nj++];
            jb.src = src; jb.dst = dst; jb.ld = ld; jb.col0 = col0;
            jb.ncols = ncols; jb.srccols = srccols;
            jb.total = nrows * ncols; jb.bstart = nb;
            nb += (jb.total + 255) / 256;
        };
        add(W_ih0, wb_ih0, 65, 0, 2048, IN0_PAD, 65);
        add(W_hh0, wb_hh0, 512, 0, 2048, 512, 512);
        add(W_ih1, wb_ih1, 512, 0, 2048, 512, 512);
        add(W_hh1, wb_hh1, 512, 0, 2048, 512, 512);
        add(pW, wb_dec,              1024, 0, 512, 512, 512);
        add(aW, wb_dec + 512 * 512,  768, 0, 512, 512, 512);
        add(iW, wb_dec + 1024 * 512, 768, 0, 512, 512, 512);
        add(cW, wb_dec + 1536 * 512, 768, 0, 512, 512, 512);
        add(aW, wb_a, 768, 512, 512, 256, 256);
        add(iW, wb_i, 768, 512, 512, 256, 256);
        add(cW, wb_c, 768, 512, 512, 256, 256);
        add(p2o_W, wb_p2o, 512, 0, 256, 512, 512);
        add(o2p_W, wb_o2p, 256, 0, 512, 256, 256);
        add(out1_W, wb_out1, 1024, 0, 1024, 1024, 1024);
        add(out2_W, wb_out2, 1024, 0, 512, 1024, 1024);
        add(mg_W, wb_mg, 512, 0, 1000, 512, 512);
        cj.nj = nj;
        conv_all<<<nb, 256, 0, stream>>>(cj);
    }
    swizzle_wp<<<1024, 256, 0, stream>>>(pW, wb_p);
    vnorm_kernel<<<3, 512, 0, stream>>>(pv, av, iv, Mv);
    concat_bias<<<8, 256, 0, stream>>>(pb, ab, ib, cb, bias_dec);

    // 1) build x
    build_x_kernel<<<B_DIM, 128, 0, stream>>>(p_ts, p_cat, emb, x_pad);

    auto gemm = [&](const float* A1, int lda1, const unsigned short* W1, int ldw1, int K1,
                    const float* A2, int lda2, const unsigned short* W2, int ldw2, int K2,
                    const float* b1, const float* b2, float* C, int ldc, int N, int relu) {
        dim3 grid((N + 63) / 64, B_DIM / 64);
        gemm_mfma<<<grid, 256, 0, stream>>>(A1, lda1, W1, ldw1, K1, A2, lda2, W2, ldw2, K2,
                                            b1, b2, C, ldc, N, relu);
    };

    // 2) LSTM layer 0 (fused ih + hh)
    gemm(x_pad, IN0_PAD, wb_ih0, IN0_PAD, IN0_PAD,
         p_hn, DD, wb_hh0, DD, DD, b_ih0, b_hh0, g_buf, 2048, 2048, 0);
    lstm_pw<<<(B_DIM * DD) / 256, 256, 0, stream>>>(g_buf, p_hc, out_hn0, out_hc0, h0_ws);

    // 3) LSTM layer 1
    gemm(h0_ws, DD, wb_ih1, DD, DD,
         p_hn + (size_t)B_DIM * DD, DD, wb_hh1, DD, DD, b_ih1, b_hh1, g_buf, 2048, 2048, 0);
    lstm_pw<<<(B_DIM * DD) / 256, 256, 0, stream>>>(g_buf, p_hc + (size_t)B_DIM * DD, out_hn1, out_hc1, h1_ws);

    // 4) all 4 dec projections in one GEMM
    gemm(h1_ws, DD, wb_dec, DD, DD, nullptr, 0, nullptr, 0, 0,
         bias_dec, nullptr, decp_all, 2048, 2048, 0);

    // 5-7) ALL THREE attentions in ONE launch, then ONE combine
    {
        dim3 ag(B_DIM, 4, 3);
        attn_all<<<ag, 512, 0, stream>>>(
            p_enc, wb_p, a_enc, i_enc, wb_a, wb_i, decp_all, 2048,
            pv, av, iv, Mv,
            part_p, part_a, part_i, lsum_p, lsum_a, lsum_i);
        dim3 cg(B_DIM, 4);
        ctx_combine3<<<cg, 256, 0, stream>>>(part_p, lsum_p, part_a, lsum_a, part_i, lsum_i,
                                             p_ctx, combined + (size_t)B_DIM * OD,
                                             combined + (size_t)2 * B_DIM * OD);
    }

    // 8) combined slot 0 = relu(p_ctx @ p2o_W^T + p2o_b)
    gemm(p_ctx, PD, wb_p2o, PD, PD, nullptr, 0, nullptr, 0, 0,
         p2o_b, nullptr, combined, OD, OD, 1);

    // 9) combiner attention over S'=3
    attn_score_mfma<256><<<(3 * B_DIM) / 64, 512, 0, stream>>>(
        combined, wb_c, decp_all + 1536, 2048, cv, score_c, 3);
    softmax_rows<<<B_DIM, 256, 0, stream>>>(score_c, 3);
    { dim3 cg(B_DIM, 1); ctx_kernel<<<cg, 256, 0, stream>>>(score_c, combined, ctx_c, 3, OD); }

    // 10) context = relu(ctx_c @ o2p_W^T + o2p_b)
    gemm(ctx_c, OD, wb_o2p, OD, OD, nullptr, 0, nullptr, 0, 0,
         o2p_b, nullptr, context, DD, DD, 1);

    // 11) h = relu([context, h1] @ out1_W^T + out1_b)
    gemm(context, DD, wb_out1, ID_DIM, DD,
         h1_ws, DD, wb_out1 + DD, ID_DIM, DD, out1_b, nullptr, h_big, ID_DIM, ID_DIM, 1);

    // 12) h2 = relu(h @ out2_W^T + out2_b)
    gemm(h_big, ID_DIM, wb_out2, ID_DIM, ID_DIM, nullptr, 0, nullptr, 0, 0,
         out2_b, nullptr, h2_buf, DD, DD, 1);

    // 13) ts
    ts_kernel<<<B_DIM, 64, 0, stream>>>(h2_buf, tg_W, tg_b, out_ts);

    // 14) cat = log_softmax(h2 @ mg_W^T + mg_b)
    gemm(h2_buf, DD, wb_mg, DD, DD, nullptr, 0, nullptr, 0, 0,
         mg_b, nullptr, logits, V_DIM, V_DIM, 0);
    log_softmax_rows<<<B_DIM, 256, 0, stream>>>(logits, out_cat, V_DIM);
}

// Round 19
// 551.541 us; speedup vs baseline: 1.0203x; 1.0203x over previous
//
#include <hip/hip_runtime.h>
#include <hip/hip_bf16.h>
#include <cstddef>

// ---------------- dims ----------------
#define S_DIM 512
#define B_DIM 256
#define PD 512
#define OD 256
#define DD 512
#define ID_DIM 1024
#define V_DIM 1000
#define EMB 64
#define IN0_PAD 96   // 1+EMB=65 padded to 96 (multiple of 32 for MFMA K)

typedef short short8 __attribute__((ext_vector_type(8)));
typedef float f32x4 __attribute__((ext_vector_type(4)));
typedef unsigned short us4 __attribute__((ext_vector_type(4)));
typedef unsigned short us8 __attribute__((ext_vector_type(8)));

// ---------------- helpers ----------------
__device__ __forceinline__ float fast_exp(float x) { return __expf(x); }
__device__ __forceinline__ float fast_tanh(float x) {
    float e = __expf(2.0f * x);
    return 1.0f - 2.0f * __builtin_amdgcn_rcpf(e + 1.0f);
}
__device__ __forceinline__ float fast_sigm(float x) {
    return __builtin_amdgcn_rcpf(1.0f + __expf(-x));
}

__device__ __forceinline__ unsigned short f2bfu(float f) {
    __hip_bfloat16 h = __float2bfloat16(f);
    return *reinterpret_cast<unsigned short*>(&h);
}
__device__ __forceinline__ float bf2f(unsigned short u) {
    unsigned int x = ((unsigned int)u) << 16;
    return __builtin_bit_cast(float, x);
}

__device__ __forceinline__ float wred_max(float v) {
#pragma unroll
    for (int o = 32; o; o >>= 1) v = fmaxf(v, __shfl_xor(v, o));
    return v;
}
__device__ __forceinline__ float wred_sum(float v) {
#pragma unroll
    for (int o = 32; o; o >>= 1) v += __shfl_xor(v, o);
    return v;
}

// ---------------- build x (padded) ----------------
__global__ __launch_bounds__(128) void build_x_kernel(
    const float* __restrict__ p_ts, const int* __restrict__ p_cat,
    const float* __restrict__ emb, float* __restrict__ x)
{
    int b = blockIdx.x, t = threadIdx.x;
    if (t < IN0_PAD) {
        float val = 0.f;
        if (t == 0) val = p_ts[b];
        else if (t < 65) val = emb[(size_t)p_cat[b] * EMB + (t - 1)];
        x[(size_t)b * IN0_PAD + t] = val;
    }
}

// ---------------- ||v||_1 for the 3 attention v vectors ----------------
__global__ __launch_bounds__(512) void vnorm_kernel(
    const float* __restrict__ pv, const float* __restrict__ av,
    const float* __restrict__ iv, float* __restrict__ Mout)
{
    const float* v = blockIdx.x == 0 ? pv : (blockIdx.x == 1 ? av : iv);
    __shared__ float tmp[8];
    const int tid = threadIdx.x;
    float x = fabsf(v[tid]);
    x = wred_sum(x);
    if ((tid & 63) == 0) tmp[tid >> 6] = x;
    __syncthreads();
    if (tid == 0) {
        float s = 0.f;
#pragma unroll
        for (int i = 0; i < 8; ++i) s += tmp[i];
        Mout[blockIdx.x] = s;
    }
}

// ---------------- concat 4 dec biases in one launch ----------------
__global__ __launch_bounds__(256) void concat_bias(
    const float* __restrict__ pb, const float* __restrict__ ab,
    const float* __restrict__ ib, const float* __restrict__ cb,
    float* __restrict__ dst)
{
    const int t = blockIdx.x * 256 + threadIdx.x;  // 0..2047
    const float* src = (t < 512) ? pb : (t < 1024 ? ab : (t < 1536 ? ib : cb));
    dst[t] = src[t & 511];
}

// ---------------- swizzle pW enc-half into MFMA fragment order ----------------
// dst element index o: e=o&7, lane=(o>>3)&63, mi=(o>>9)&3, ks=(o>>11)&15, w=o>>15.
// Value = pW[row][512+col], row = w*64 + mi*16 + (lane&15),
// col = ks*32 + (lane>>4)*8 + e. Fragment (w,ks,mi) = contiguous 1 KB block.
__global__ __launch_bounds__(256) void swizzle_wp(
    const float* __restrict__ pW, unsigned short* __restrict__ dst)
{
    const int o = blockIdx.x * 256 + threadIdx.x;
    const int e    = o & 7;
    const int lane = (o >> 3) & 63;
    const int mi   = (o >> 9) & 3;
    const int ks   = (o >> 11) & 15;
    const int w    = o >> 15;
    const int row = (w << 6) + (mi << 4) + (lane & 15);
    const int col = (ks << 5) + ((lane >> 4) << 3) + e;
    dst[o] = f2bfu(pW[(size_t)row * 1024 + 512 + col]);
}

// ---------------- fused multi-job f32 -> bf16 weight convert ----------------
struct ConvJob {
    const float* src; unsigned short* dst;
    int ld, col0, ncols, srccols, bstart, total;
};
struct ConvJobs { ConvJob j[17]; int nj; };

__global__ __launch_bounds__(256) void conv_all(ConvJobs jobs)
{
    const int blk = blockIdx.x;
    int ji = 0;
#pragma unroll
    for (int k = 1; k < 17; ++k)
        if (k < jobs.nj && jobs.j[k].bstart <= blk) ji = k;
    const ConvJob jb = jobs.j[ji];
    const int idx = (blk - jb.bstart) * 256 + threadIdx.x;
    if (idx >= jb.total) return;
    const int r = idx / jb.ncols, c = idx - r * jb.ncols;
    const float v = (c < jb.srccols) ? jb.src[(size_t)r * jb.ld + jb.col0 + c] : 0.f;
    jb.dst[idx] = f2bfu(v);
}

// ---------------- bf16 MFMA GEMM: C = act(A1@W1^T [+ A2@W2^T] + b1 [+ b2]) ----------------
__global__ __launch_bounds__(256) void gemm_mfma(
    const float* __restrict__ A1, int lda1,
    const unsigned short* __restrict__ W1, int ldw1, int K1,
    const float* __restrict__ A2, int lda2,
    const unsigned short* __restrict__ W2, int ldw2, int K2,
    const float* __restrict__ bias1, const float* __restrict__ bias2,
    float* __restrict__ C, int ldc, int N, int relu)
{
    __shared__ alignas(16) unsigned short As[64][40];
    __shared__ alignas(16) unsigned short Ws[64][40];
    const int tid = threadIdx.x;
    const int l = tid & 63, wvid = tid >> 6;
    const int wx = wvid & 1, wy = wvid >> 1;
    const int bm = blockIdx.y << 6, bn = blockIdx.x << 6;
    const int sr = tid >> 2, sc = (tid & 3) << 3;
    const int lk = (l >> 4) << 3;
    f32x4 acc[2][2] = {};

    for (int pass = 0; pass < 2; ++pass) {
        const float* A = pass ? A2 : A1;
        if (!A) continue;
        const unsigned short* W = pass ? W2 : W1;
        const int lda = pass ? lda2 : lda1;
        const int ldw = pass ? ldw2 : ldw1;
        const int K = pass ? K2 : K1;
        for (int k0 = 0; k0 < K; k0 += 32) {
            const float* ap = A + (size_t)(bm + sr) * lda + k0 + sc;
            float4 a0 = *reinterpret_cast<const float4*>(ap);
            float4 a1 = *reinterpret_cast<const float4*>(ap + 4);
            us8 pk = { f2bfu(a0.x), f2bfu(a0.y), f2bfu(a0.z), f2bfu(a0.w),
                       f2bfu(a1.x), f2bfu(a1.y), f2bfu(a1.z), f2bfu(a1.w) };
            *reinterpret_cast<us8*>(&As[sr][sc]) = pk;
            const int wr = bn + sr;
            short8 wvv = { 0, 0, 0, 0, 0, 0, 0, 0 };
            if (wr < N) wvv = *reinterpret_cast<const short8*>(W + (size_t)wr * ldw + k0 + sc);
            *reinterpret_cast<short8*>(&Ws[sr][sc]) = wvv;
            __syncthreads();
            short8 wf[2], af[2];
#pragma unroll
            for (int i = 0; i < 2; ++i) {
                wf[i] = *reinterpret_cast<const short8*>(&Ws[(wx << 5) + (i << 4) + (l & 15)][lk]);
                af[i] = *reinterpret_cast<const short8*>(&As[(wy << 5) + (i << 4) + (l & 15)][lk]);
            }
#pragma unroll
            for (int wi = 0; wi < 2; ++wi)
#pragma unroll
                for (int ai = 0; ai < 2; ++ai)
                    acc[wi][ai] = __builtin_amdgcn_mfma_f32_16x16x32_bf16(wf[wi], af[ai], acc[wi][ai], 0, 0, 0);
            __syncthreads();
        }
    }

#pragma unroll
    for (int wi = 0; wi < 2; ++wi) {
#pragma unroll
        for (int ai = 0; ai < 2; ++ai) {
            const int n0 = bn + (wx << 5) + (wi << 4) + ((l >> 4) << 2);
            const int m  = bm + (wy << 5) + (ai << 4) + (l & 15);
            if (n0 >= N) continue;
            f32x4 a = acc[wi][ai];
            float4 r = make_float4(a.x, a.y, a.z, a.w);
            if (bias1) {
                float4 b = *reinterpret_cast<const float4*>(bias1 + n0);
                r.x += b.x; r.y += b.y; r.z += b.z; r.w += b.w;
            }
            if (bias2) {
                float4 b = *reinterpret_cast<const float4*>(bias2 + n0);
                r.x += b.x; r.y += b.y; r.z += b.z; r.w += b.w;
            }
            if (relu) {
                r.x = fmaxf(r.x, 0.f); r.y = fmaxf(r.y, 0.f);
                r.z = fmaxf(r.z, 0.f); r.w = fmaxf(r.w, 0.f);
            }
            *reinterpret_cast<float4*>(&C[(size_t)m * ldc + n0]) = r;
        }
    }
}

// ---------------- FUSED attention (E=512, p), SWIZZLED Wb, 32-row single-buffer ----------------
// r19 = r17/r15/r13 proven local optimum (185 us, 46% occupancy, VGPR 64).
// Closed knobs (counter-evidenced): 64-row tiles (r16, occupancy loss),
// LDS dbuf (r12), register prefetch (r14), merged attn_all (r18).
template<int E>
__global__ __launch_bounds__(512, 2) void attn_fused(
    const float* __restrict__ enc,
    const unsigned short* __restrict__ Wsw,
    const float* __restrict__ decp, int ldd,
    const float* __restrict__ v,
    const float* __restrict__ Mptr,
    float* __restrict__ ctx_part,
    float* __restrict__ lsum)
{
    constexpr int LROW = E + 8;
    constexpr int NT   = 4;
    constexpr int NF4  = E / 64;
    constexpr int NKS  = E / 32;
    __shared__ alignas(16) unsigned short encL[32][LROW];
    __shared__ float red[32][9];
    __shared__ float wexp[32];
    const int tid = threadIdx.x;
    const int w = tid >> 6, l = tid & 63;
    const int b = blockIdx.x, z = blockIdx.y;
    const int s0 = z << 7;
    const float M = Mptr[0];

    const int srow = tid >> 4;
    const int sq = tid & 15;
    const float* encb = enc + (size_t)b * E;
    const int lk = (l >> 4) << 3;
    const unsigned short* wswz = Wsw + ((size_t)w * NKS * 4 * 512) + (l << 3);
    const int nb0 = (w << 6) + ((l >> 4) << 2);
    const float* drow = decp + (size_t)b * ldd + nb0;

    float ctx_acc = 0.f, l_acc = 0.f;

#pragma unroll 1
    for (int t = 0; t < NT; ++t) {
        // ---- stage 32-row tile (full-MLP loads) ----
        {
            const float* rowp = encb + (size_t)(s0 + (t << 5) + srow) * B_DIM * E;
            float4 r[NF4];
#pragma unroll
            for (int j = 0; j < NF4; ++j)
                r[j] = *reinterpret_cast<const float4*>(rowp + ((sq + (j << 4)) << 2));
#pragma unroll
            for (int j = 0; j < NF4; ++j) {
                us4 pk = { f2bfu(r[j].x), f2bfu(r[j].y), f2bfu(r[j].z), f2bfu(r[j].w) };
                *reinterpret_cast<us4*>(&encL[srow][(sq + (j << 4)) << 2]) = pk;
            }
        }
        __syncthreads();

        // ---- score MFMA: afr = contiguous swizzled stream ----
        f32x4 acc[4][2] = {};
#pragma unroll 4
        for (int ks = 0; ks < NKS; ++ks) {
            short8 bfr[2];
#pragma unroll
            for (int ni = 0; ni < 2; ++ni)
                bfr[ni] = *reinterpret_cast<const short8*>(
                    &encL[(ni << 4) + (l & 15)][(ks << 5) + lk]);
#pragma unroll
            for (int mi = 0; mi < 4; ++mi) {
                short8 afr = *reinterpret_cast<const short8*>(wswz + (((ks << 2) + mi) << 9));
#pragma unroll
                for (int ni = 0; ni < 2; ++ni)
                    acc[mi][ni] = __builtin_amdgcn_mfma_f32_16x16x32_bf16(afr, bfr[ni], acc[mi][ni], 0, 0, 0);
            }
        }

        // ---- tanh + v-dot ----
        float p0 = 0.f, p1 = 0.f;
#pragma unroll
        for (int mi = 0; mi < 4; ++mi) {
            float4 d   = *reinterpret_cast<const float4*>(drow + (mi << 4));
            float4 vvm = *reinterpret_cast<const float4*>(v + nb0 + (mi << 4));
            f32x4 a0 = acc[mi][0];
            p0 += fast_tanh(a0.x + d.x) * vvm.x;
            p0 += fast_tanh(a0.y + d.y) * vvm.y;
            p0 += fast_tanh(a0.z + d.z) * vvm.z;
            p0 += fast_tanh(a0.w + d.w) * vvm.w;
            f32x4 a1 = acc[mi][1];
            p1 += fast_tanh(a1.x + d.x) * vvm.x;
            p1 += fast_tanh(a1.y + d.y) * vvm.y;
            p1 += fast_tanh(a1.z + d.z) * vvm.z;
            p1 += fast_tanh(a1.w + d.w) * vvm.w;
        }
        p0 += __shfl_xor(p0, 16); p0 += __shfl_xor(p0, 32);
        p1 += __shfl_xor(p1, 16); p1 += __shfl_xor(p1, 32);
        if (l < 16) { red[l][w] = p0; red[16 + l][w] = p1; }
        __syncthreads();

        if (tid < 32) {
            float ssum = 0.f;
#pragma unroll
            for (int ww = 0; ww < 8; ++ww) ssum += red[tid][ww];
            float wsv = fast_exp(ssum - M);
            wexp[tid] = wsv;
            float t2 = wsv;
            t2 += __shfl_xor(t2, 16); t2 += __shfl_xor(t2, 8);
            t2 += __shfl_xor(t2, 4);  t2 += __shfl_xor(t2, 2);
            t2 += __shfl_xor(t2, 1);
            if (tid == 0) l_acc += t2;
        }
        __syncthreads();

        // ---- context accumulation from the same LDS tile ----
        if (tid < E) {
            float a = 0.f;
#pragma unroll 8
            for (int s = 0; s < 32; ++s)
                a += wexp[s] * bf2f(encL[s][tid]);
            ctx_acc += a;
        }
        __syncthreads();
    }

    if (tid < E)
        ctx_part[((size_t)z * B_DIM + b) * E + tid] = ctx_acc;
    if (tid == 0)
        lsum[z * B_DIM + b] = l_acc;
}

// ---------------- FUSED a+i attentions in ONE launch (E=256, Wb in regs) ----------------
__global__ __launch_bounds__(512, 2) void attn_fused_wreg2(
    const float* __restrict__ enc_a, const float* __restrict__ enc_i,
    const unsigned short* __restrict__ Wb_a, const unsigned short* __restrict__ Wb_i,
    const float* __restrict__ decp_a, const float* __restrict__ decp_i, int ldd,
    const float* __restrict__ va, const float* __restrict__ vi,
    const float* __restrict__ Mptr_a, const float* __restrict__ Mptr_i,
    float* __restrict__ part_a_, float* __restrict__ part_i_,
    float* __restrict__ lsum_a_, float* __restrict__ lsum_i_)
{
    constexpr int E = 256;
    constexpr int LROW = E + 8;
    constexpr int NT = 4;
    constexpr int NF4 = E / 64;   // 4
    __shared__ alignas(16) unsigned short encL[2][32][LROW];
    __shared__ float red[32][9];
    __shared__ float wexp[32];
    const int tid = threadIdx.x;
    const int w = tid >> 6, l = tid & 63;
    const int b = blockIdx.x, z = blockIdx.y;
    const int sel = blockIdx.z;
    const float* enc  = sel ? enc_i  : enc_a;
    const unsigned short* Wb = sel ? Wb_i : Wb_a;
    const float* decp = sel ? decp_i : decp_a;
    const float* v    = sel ? vi     : va;
    const float M     = sel ? Mptr_i[0] : Mptr_a[0];
    float* ctx_part   = sel ? part_i_ : part_a_;
    float* lsum       = sel ? lsum_i_ : lsum_a_;
    const int s0 = z << 7;

    const int srow = tid >> 4;
    const int sq = tid & 15;
    const float* encb = enc + (size_t)b * E;
    const int lk = (l >> 4) << 3;
    const unsigned short* wbase = Wb + (size_t)((w << 6) + (l & 15)) * E + lk;
    const int nb0 = (w << 6) + ((l >> 4) << 2);
    const float* drow = decp + (size_t)b * ldd + nb0;

    short8 afrA[4][4], afrB[4][4];
#pragma unroll
    for (int mi = 0; mi < 4; ++mi) {
#pragma unroll
        for (int j = 0; j < 4; ++j) {
            afrA[mi][j] = *reinterpret_cast<const short8*>(wbase + (size_t)(mi << 4) * E + (j << 5));
            afrB[mi][j] = *reinterpret_cast<const short8*>(wbase + (size_t)(mi << 4) * E + ((j + 4) << 5));
        }
    }

    {
        const float* rowp = encb + (size_t)(s0 + srow) * B_DIM * E;
        float4 r[NF4];
#pragma unroll
        for (int j = 0; j < NF4; ++j)
            r[j] = *reinterpret_cast<const float4*>(rowp + ((sq + (j << 4)) << 2));
#pragma unroll
        for (int j = 0; j < NF4; ++j) {
            us4 pk = { f2bfu(r[j].x), f2bfu(r[j].y), f2bfu(r[j].z), f2bfu(r[j].w) };
            *reinterpret_cast<us4*>(&encL[0][srow][(sq + (j << 4)) << 2]) = pk;
        }
    }
    __syncthreads();

    float ctx_acc = 0.f, l_acc = 0.f;
    int cur = 0;

#pragma unroll 1
    for (int t = 0; t < NT; ++t) {
        float4 rn[NF4];
        const bool more = (t + 1) < NT;
        if (more) {
            const float* rowp = encb + (size_t)(s0 + ((t + 1) << 5) + srow) * B_DIM * E;
#pragma unroll
            for (int j = 0; j < NF4; ++j)
                rn[j] = *reinterpret_cast<const float4*>(rowp + ((sq + (j << 4)) << 2));
        }

        f32x4 acc[4][2] = {};
#pragma unroll
        for (int j = 0; j < 4; ++j) {
            short8 b0 = *reinterpret_cast<const short8*>(&encL[cur][(l & 15)][(j << 5) + lk]);
            short8 b1 = *reinterpret_cast<const short8*>(&encL[cur][16 + (l & 15)][(j << 5) + lk]);
#pragma unroll
            for (int mi = 0; mi < 4; ++mi) {
                acc[mi][0] = __builtin_amdgcn_mfma_f32_16x16x32_bf16(afrA[mi][j], b0, acc[mi][0], 0, 0, 0);
                acc[mi][1] = __builtin_amdgcn_mfma_f32_16x16x32_bf16(afrA[mi][j], b1, acc[mi][1], 0, 0, 0);
            }
        }
#pragma unroll
        for (int j = 0; j < 4; ++j) {
            short8 b0 = *reinterpret_cast<const short8*>(&encL[cur][(l & 15)][((j + 4) << 5) + lk]);
            short8 b1 = *reinterpret_cast<const short8*>(&encL[cur][16 + (l & 15)][((j + 4) << 5) + lk]);
#pragma unroll
            for (int mi = 0; mi < 4; ++mi) {
                acc[mi][0] = __builtin_amdgcn_mfma_f32_16x16x32_bf16(afrB[mi][j], b0, acc[mi][0], 0, 0, 0);
                acc[mi][1] = __builtin_amdgcn_mfma_f32_16x16x32_bf16(afrB[mi][j], b1, acc[mi][1], 0, 0, 0);
            }
        }

        float p0 = 0.f, p1 = 0.f;
#pragma unroll
        for (int mi = 0; mi < 4; ++mi) {
            float4 d   = *reinterpret_cast<const float4*>(drow + (mi << 4));
            float4 vvm = *reinterpret_cast<const float4*>(v + nb0 + (mi << 4));
            f32x4 a0 = acc[mi][0];
            p0 += fast_tanh(a0.x + d.x) * vvm.x;
            p0 += fast_tanh(a0.y + d.y) * vvm.y;
            p0 += fast_tanh(a0.z + d.z) * vvm.z;
            p0 += fast_tanh(a0.w + d.w) * vvm.w;
            f32x4 a1 = acc[mi][1];
            p1 += fast_tanh(a1.x + d.x) * vvm.x;
            p1 += fast_tanh(a1.y + d.y) * vvm.y;
            p1 += fast_tanh(a1.z + d.z) * vvm.z;
            p1 += fast_tanh(a1.w + d.w) * vvm.w;
        }
        p0 += __shfl_xor(p0, 16); p0 += __shfl_xor(p0, 32);
        p1 += __shfl_xor(p1, 16); p1 += __shfl_xor(p1, 32);
        if (l < 16) { red[l][w] = p0; red[16 + l][w] = p1; }
        __syncthreads();

        if (tid < 32) {
            float ssum = 0.f;
#pragma unroll
            for (int ww = 0; ww < 8; ++ww) ssum += red[tid][ww];
            float wsv = fast_exp(ssum - M);
            wexp[tid] = wsv;
            float t2 = wsv;
            t2 += __shfl_xor(t2, 16); t2 += __shfl_xor(t2, 8);
            t2 += __shfl_xor(t2, 4);  t2 += __shfl_xor(t2, 2);
            t2 += __shfl_xor(t2, 1);
            if (tid == 0) l_acc += t2;
        }
        __syncthreads();

        if (tid < E) {
            float a = 0.f;
#pragma unroll 8
            for (int s = 0; s < 32; ++s)
                a += wexp[s] * bf2f(encL[cur][s][tid]);
            ctx_acc += a;
        }

        if (more) {
#pragma unroll
            for (int j = 0; j < NF4; ++j) {
                us4 pk = { f2bfu(rn[j].x), f2bfu(rn[j].y), f2bfu(rn[j].z), f2bfu(rn[j].w) };
                *reinterpret_cast<us4*>(&encL[cur ^ 1][srow][(sq + (j << 4)) << 2]) = pk;
            }
        }
        __syncthreads();
        cur ^= 1;
    }

    if (tid < E)
        ctx_part[((size_t)z * B_DIM + b) * E + tid] = ctx_acc;
    if (tid == 0)
        lsum[z * B_DIM + b] = l_acc;
}

// ---------------- ONE-launch combine for all three attentions ----------------
// grid (B, 4): y=0 -> p cols 0..255; y=1 -> p cols 256..511; y=2 -> a; y=3 -> i.
__global__ __launch_bounds__(256) void ctx_combine3(
    const float* __restrict__ part_p, const float* __restrict__ lsum_p,
    const float* __restrict__ part_a, const float* __restrict__ lsum_a,
    const float* __restrict__ part_i, const float* __restrict__ lsum_i,
    float* __restrict__ p_ctx, float* __restrict__ comb_a, float* __restrict__ comb_i)
{
    const int b = blockIdx.x, y = blockIdx.y;
    const float* part; const float* lsum; float* out; int E, e;
    if (y < 2)      { part = part_p; lsum = lsum_p; out = p_ctx;  E = 512; e = (y << 8) + threadIdx.x; }
    else if (y == 2){ part = part_a; lsum = lsum_a; out = comb_a; E = 256; e = threadIdx.x; }
    else            { part = part_i; lsum = lsum_i; out = comb_i; E = 256; e = threadIdx.x; }
    const float ls = lsum[b] + lsum[B_DIM + b] + lsum[2 * B_DIM + b] + lsum[3 * B_DIM + b];
    const size_t BE = (size_t)B_DIM * E;
    const size_t idx = (size_t)b * E + e;
    const float s = part[idx] + part[BE + idx] + part[2 * BE + idx] + part[3 * BE + idx];
    out[idx] = s * __builtin_amdgcn_rcpf(ls);
}

// ---------------- MFMA attention score (combiner only, Sdim=3) ----------------
template<int E>
__global__ __launch_bounds__(512, 4) void attn_score_mfma(
    const float* __restrict__ enc,
    const unsigned short* __restrict__ Wb,
    const float* __restrict__ decp, int ldd,
    const float* __restrict__ v,
    float* __restrict__ score, int Sdim)
{
    __shared__ alignas(16) unsigned short Al[64][E + 8];
    __shared__ float red[64][9];
    const int tid = threadIdx.x;
    const int w = tid >> 6, l = tid & 63;
    const int m0 = blockIdx.x << 6;
    constexpr int NKS = E >> 5;

    const int srow = tid >> 3;
    const int scol = (tid & 7) << 3;
    {
        const float* srcp = enc + (size_t)(m0 + srow) * E + scol;
        float4 a0 = *reinterpret_cast<const float4*>(srcp);
        float4 a1 = *reinterpret_cast<const float4*>(srcp + 4);
        us8 pk = { f2bfu(a0.x), f2bfu(a0.y), f2bfu(a0.z), f2bfu(a0.w),
                   f2bfu(a1.x), f2bfu(a1.y), f2bfu(a1.z), f2bfu(a1.w) };
        *reinterpret_cast<us8*>(&Al[srow][scol]) = pk;
    }
    __syncthreads();

    f32x4 acc[4][4] = {};
    const int lk = (l >> 4) << 3;
    const unsigned short* wbase = Wb + (size_t)((w << 6) + (l & 15)) * E + lk;

#pragma unroll 2
    for (int ks = 0; ks < NKS; ++ks) {
        short8 bfr[4];
#pragma unroll
        for (int ni = 0; ni < 4; ++ni)
            bfr[ni] = *reinterpret_cast<const short8*>(&Al[(ni << 4) + (l & 15)][(ks << 5) + lk]);
#pragma unroll
        for (int mi = 0; mi < 4; ++mi) {
            short8 afr = *reinterpret_cast<const short8*>(wbase + (size_t)(mi << 4) * E + (ks << 5));
#pragma unroll
            for (int ni = 0; ni < 4; ++ni)
                acc[mi][ni] = __builtin_amdgcn_mfma_f32_16x16x32_bf16(afr, bfr[ni], acc[mi][ni], 0, 0, 0);
        }
    }

    const int nb0 = (w << 6) + ((l >> 4) << 2);
#pragma unroll
    for (int ni = 0; ni < 4; ++ni) {
        const int ml = (ni << 4) + (l & 15);
        const int b = (m0 + ml) & (B_DIM - 1);
        const float* drow = decp + (size_t)b * ldd + nb0;
        float p = 0.f;
#pragma unroll
        for (int mi = 0; mi < 4; ++mi) {
            float4 d = *reinterpret_cast<const float4*>(drow + (mi << 4));
            float4 vvm = *reinterpret_cast<const float4*>(v + nb0 + (mi << 4));
            f32x4 a = acc[mi][ni];
            p += fast_tanh(a.x + d.x) * vvm.x;
            p += fast_tanh(a.y + d.y) * vvm.y;
            p += fast_tanh(a.z + d.z) * vvm.z;
            p += fast_tanh(a.w + d.w) * vvm.w;
        }
        p += __shfl_xor(p, 16);
        p += __shfl_xor(p, 32);
        if (l < 16) red[(ni << 4) + l][w] = p;
    }
    __syncthreads();
    if (tid < 64) {
        float ssum = 0.f;
#pragma unroll
        for (int ww = 0; ww < 8; ++ww) ssum += red[tid][ww];
        const int m = m0 + tid;
        score[(size_t)(m & (B_DIM - 1)) * Sdim + (m >> 8)] = ssum;
    }
}

// ---------------- softmax rows in place: x [B, Sdim] ----------------
__global__ __launch_bounds__(256) void softmax_rows(float* __restrict__ x, int Sdim)
{
    const int b = blockIdx.x, tid = threadIdx.x;
    const int lane = tid & 63, wid = tid >> 6;
    float* row = x + (size_t)b * Sdim;
    __shared__ float tmp[4];
    float m = -3.4e38f;
    for (int s = tid; s < Sdim; s += 256) m = fmaxf(m, row[s]);
    m = wred_max(m);
    if (lane == 0) tmp[wid] = m;
    __syncthreads();
    m = fmaxf(fmaxf(tmp[0], tmp[1]), fmaxf(tmp[2], tmp[3]));
    __syncthreads();
    float sum = 0.f;
    for (int s = tid; s < Sdim; s += 256) { float e = fast_exp(row[s] - m); row[s] = e; sum += e; }
    sum = wred_sum(sum);
    if (lane == 0) tmp[wid] = sum;
    __syncthreads();
    sum = tmp[0] + tmp[1] + tmp[2] + tmp[3];
    const float inv = 1.0f / sum;
    for (int s = tid; s < Sdim; s += 256) row[s] *= inv;
}

// ---------------- small weighted context (combiner, Sdim=3) ----------------
__global__ __launch_bounds__(256) void ctx_kernel(
    const float* __restrict__ w, const float* __restrict__ enc,
    float* __restrict__ out, int Sdim, int E)
{
    const int b = blockIdx.x;
    const int e = blockIdx.y * 256 + threadIdx.x;
    if (e >= E) return;
    const float* wr = w + (size_t)b * Sdim;
    float acc = 0.f;
    for (int s = 0; s < Sdim; ++s)
        acc += wr[s] * enc[((size_t)s * B_DIM + b) * E + e];
    out[(size_t)b * E + e] = acc;
}

// ---------------- LSTM pointwise ----------------
__global__ __launch_bounds__(256) void lstm_pw(
    const float* __restrict__ g, const float* __restrict__ cprev,
    float* __restrict__ h_out, float* __restrict__ c_out, float* __restrict__ h_copy)
{
    const int idx = blockIdx.x * 256 + threadIdx.x;
    const int b = idx >> 9, d = idx & 511;
    const float* gr = g + (size_t)b * 2048;
    const float ig = fast_sigm(gr[d]);
    const float fg = fast_sigm(gr[512 + d]);
    const float gg = fast_tanh(gr[1024 + d]);
    const float og = fast_sigm(gr[1536 + d]);
    const float c2 = fg * cprev[idx] + ig * gg;
    const float h2 = og * fast_tanh(c2);
    h_out[idx] = h2; c_out[idx] = c2; h_copy[idx] = h2;
}

// ---------------- ts head ----------------
__global__ __launch_bounds__(64) void ts_kernel(
    const float* __restrict__ h2, const float* __restrict__ tgW,
    const float* __restrict__ tgb, float* __restrict__ out)
{
    const int b = blockIdx.x, t = threadIdx.x;
    float s = 0.f;
    for (int d = t; d < 512; d += 64) s += h2[(size_t)b * 512 + d] * tgW[d];
    s = wred_sum(s);
    if (t == 0) out[b] = fmaxf(s + tgb[0], 0.f);
}

// ---------------- log softmax rows ----------------
__global__ __launch_bounds__(256) void log_softmax_rows(
    const float* __restrict__ in, float* __restrict__ out, int V)
{
    const int b = blockIdx.x, tid = threadIdx.x;
    const int lane = tid & 63, wid = tid >> 6;
    const float* row = in + (size_t)b * V;
    float* orow = out + (size_t)b * V;
    __shared__ float tmp[4];
    float m = -3.4e38f;
    for (int s = tid; s < V; s += 256) m = fmaxf(m, row[s]);
    m = wred_max(m);
    if (lane == 0) tmp[wid] = m;
    __syncthreads();
    m = fmaxf(fmaxf(tmp[0], tmp[1]), fmaxf(tmp[2], tmp[3]));
    __syncthreads();
    float sum = 0.f;
    for (int s = tid; s < V; s += 256) sum += fast_exp(row[s] - m);
    sum = wred_sum(sum);
    if (lane == 0) tmp[wid] = sum;
    __syncthreads();
    sum = tmp[0] + tmp[1] + tmp[2] + tmp[3];
    const float lse = m + logf(sum);
    for (int s = tid; s < V; s += 256) orow[s] = row[s] - lse;
}

// ---------------- host ----------------
extern "C" void kernel_launch(void* const* d_in, const int* in_sizes, int n_in,
                              void* d_out, int out_size, void* d_ws, size_t ws_size,
                              hipStream_t stream)
{
    const float* p_ts   = (const float*)d_in[0];
    const int*   p_cat  = (const int*)d_in[1];
    const float* p_hn   = (const float*)d_in[2];
    const float* p_hc   = (const float*)d_in[3];
    const float* p_enc  = (const float*)d_in[4];
    const float* a_enc  = (const float*)d_in[5];
    const float* i_enc  = (const float*)d_in[6];
    const float* emb    = (const float*)d_in[7];
    const float* W_ih0  = (const float*)d_in[8];
    const float* W_hh0  = (const float*)d_in[9];
    const float* b_ih0  = (const float*)d_in[10];
    const float* b_hh0  = (const float*)d_in[11];
    const float* W_ih1  = (const float*)d_in[12];
    const float* W_hh1  = (const float*)d_in[13];
    const float* b_ih1  = (const float*)d_in[14];
    const float* b_hh1  = (const float*)d_in[15];
    const float* pW = (const float*)d_in[16]; const float* pb = (const float*)d_in[17]; const float* pv = (const float*)d_in[18];
    const float* aW = (const float*)d_in[19]; const float* ab = (const float*)d_in[20]; const float* av = (const float*)d_in[21];
    const float* iW = (const float*)d_in[22]; const float* ib = (const float*)d_in[23]; const float* iv = (const float*)d_in[24];
    const float* cW = (const float*)d_in[25]; const float* cb = (const float*)d_in[26]; const float* cv = (const float*)d_in[27];
    const float* p2o_W = (const float*)d_in[28]; const float* p2o_b = (const float*)d_in[29];
    const float* o2p_W = (const float*)d_in[30]; const float* o2p_b = (const float*)d_in[31];
    const float* out1_W = (const float*)d_in[32]; const float* out1_b = (const float*)d_in[33];
    const float* out2_W = (const float*)d_in[34]; const float* out2_b = (const float*)d_in[35];
    const float* mg_W = (const float*)d_in[36]; const float* mg_b = (const float*)d_in[37];
    const float* tg_W = (const float*)d_in[38]; const float* tg_b = (const float*)d_in[39];

    float* out = (float*)d_out;
    float* ws  = (float*)d_ws;

    // ---- output offsets (floats) ----
    float* out_ts  = out;
    float* out_cat = out + 256;
    float* out_hn0 = out + 256256;
    float* out_hn1 = out + 256256 + 131072;
    float* out_hc0 = out + 518400;
    float* out_hc1 = out + 518400 + 131072;

    // ---- workspace layout (floats) ----
    size_t off = 0;
    float* x_pad    = ws + off; off += (size_t)B_DIM * IN0_PAD;
    float* g_buf    = ws + off; off += (size_t)B_DIM * 2048;      // aliased: part_p / h_big+logits
    float* h0_ws    = ws + off; off += (size_t)B_DIM * DD;
    float* h1_ws    = ws + off; off += (size_t)B_DIM * DD;
    float* decp_all = ws + off; off += (size_t)B_DIM * 2048;
    float* score_c  = ws + off; off += 1024;
    float* Mv       = ws + off; off += 16;
    float* p_ctx    = ws + off; off += (size_t)B_DIM * PD;
    float* combined = ws + off; off += (size_t)3 * B_DIM * OD;
    float* ctx_c    = ws + off; off += (size_t)B_DIM * OD;
    float* context  = ws + off; off += (size_t)B_DIM * DD;
    float* h2_buf   = ws + off; off += (size_t)B_DIM * DD;
    float* bias_dec = ws + off; off += 2048;
    float* part_a   = ws + off; off += (size_t)4 * B_DIM * OD;
    float* part_i   = ws + off; off += (size_t)4 * B_DIM * OD;
    float* lsum_p   = ws + off; off += 1024;
    float* lsum_a   = ws + off; off += 1024;
    float* lsum_i   = ws + off; off += 1024;
    unsigned short* wb_base = (unsigned short*)(ws + off);
    size_t uo = 0;
    unsigned short* wb_ih0  = wb_base + uo; uo += (size_t)2048 * IN0_PAD;
    unsigned short* wb_hh0  = wb_base + uo; uo += (size_t)2048 * 512;
    unsigned short* wb_ih1  = wb_base + uo; uo += (size_t)2048 * 512;
    unsigned short* wb_hh1  = wb_base + uo; uo += (size_t)2048 * 512;
    unsigned short* wb_dec  = wb_base + uo; uo += (size_t)2048 * 512;
    unsigned short* wb_p    = wb_base + uo; uo += (size_t)512 * 512;   // SWIZZLED fragment order
    unsigned short* wb_a    = wb_base + uo; uo += (size_t)512 * 256;
    unsigned short* wb_i    = wb_base + uo; uo += (size_t)512 * 256;
    unsigned short* wb_c    = wb_base + uo; uo += (size_t)512 * 256;
    unsigned short* wb_p2o  = wb_base + uo; uo += (size_t)256 * 512;
    unsigned short* wb_o2p  = wb_base + uo; uo += (size_t)512 * 256;
    unsigned short* wb_out1 = wb_base + uo; uo += (size_t)1024 * 1024;
    unsigned short* wb_out2 = wb_base + uo; uo += (size_t)512 * 1024;
    unsigned short* wb_mg   = wb_base + uo; uo += (size_t)1000 * 512;
    float* part_p = g_buf;
    float* h_big  = g_buf;
    float* logits = g_buf + 262144;
    (void)ws_size; (void)n_in; (void)in_sizes; (void)out_size;

    // 0) convert weights to bf16 (one launch) + swizzled p-attn W; v norms; biases
    {
        ConvJobs cj; int nj = 0, nb = 0;
        auto add = [&](const float* src, unsigned short* dst, int ld, int col0,
                       int nrows, int ncols, int srccols) {
            ConvJob& jb = cj.j[nj++];
            jb.src = src; jb.dst = dst; jb.ld = ld; jb.col0 = col0;
            jb.ncols = ncols; jb.srccols = srccols;
            jb.total = nrows * ncols; jb.bstart = nb;
            nb += (jb.total + 255) / 256;
        };
        add(W_ih0, wb_ih0, 65, 0, 2048, IN0_PAD, 65);
        add(W_hh0, wb_hh0, 512, 0, 2048, 512, 512);
        add(W_ih1, wb_ih1, 512, 0, 2048, 512, 512);
        add(W_hh1, wb_hh1, 512, 0, 2048, 512, 512);
        add(pW, wb_dec,              1024, 0, 512, 512, 512);
        add(aW, wb_dec + 512 * 512,  768, 0, 512, 512, 512);
        add(iW, wb_dec + 1024 * 512, 768, 0, 512, 512, 512);
        add(cW, wb_dec + 1536 * 512, 768, 0, 512, 512, 512);
        add(aW, wb_a, 768, 512, 512, 256, 256);
        add(iW, wb_i, 768, 512, 512, 256, 256);
        add(cW, wb_c, 768, 512, 512, 256, 256);
        add(p2o_W, wb_p2o, 512, 0, 256, 512, 512);
        add(o2p_W, wb_o2p, 256, 0, 512, 256, 256);
        add(out1_W, wb_out1, 1024, 0, 1024, 1024, 1024);
        add(out2_W, wb_out2, 1024, 0, 512, 1024, 1024);
        add(mg_W, wb_mg, 512, 0, 1000, 512, 512);
        cj.nj = nj;
        conv_all<<<nb, 256, 0, stream>>>(cj);
    }
    swizzle_wp<<<1024, 256, 0, stream>>>(pW, wb_p);
    vnorm_kernel<<<3, 512, 0, stream>>>(pv, av, iv, Mv);
    concat_bias<<<8, 256, 0, stream>>>(pb, ab, ib, cb, bias_dec);

    // 1) build x
    build_x_kernel<<<B_DIM, 128, 0, stream>>>(p_ts, p_cat, emb, x_pad);

    auto gemm = [&](const float* A1, int lda1, const unsigned short* W1, int ldw1, int K1,
                    const float* A2, int lda2, const unsigned short* W2, int ldw2, int K2,
                    const float* b1, const float* b2, float* C, int ldc, int N, int relu) {
        dim3 grid((N + 63) / 64, B_DIM / 64);
        gemm_mfma<<<grid, 256, 0, stream>>>(A1, lda1, W1, ldw1, K1, A2, lda2, W2, ldw2, K2,
                                            b1, b2, C, ldc, N, relu);
    };

    // 2) LSTM layer 0 (fused ih + hh)
    gemm(x_pad, IN0_PAD, wb_ih0, IN0_PAD, IN0_PAD,
         p_hn, DD, wb_hh0, DD, DD, b_ih0, b_hh0, g_buf, 2048, 2048, 0);
    lstm_pw<<<(B_DIM * DD) / 256, 256, 0, stream>>>(g_buf, p_hc, out_hn0, out_hc0, h0_ws);

    // 3) LSTM layer 1
    gemm(h0_ws, DD, wb_ih1, DD, DD,
         p_hn + (size_t)B_DIM * DD, DD, wb_hh1, DD, DD, b_ih1, b_hh1, g_buf, 2048, 2048, 0);
    lstm_pw<<<(B_DIM * DD) / 256, 256, 0, stream>>>(g_buf, p_hc + (size_t)B_DIM * DD, out_hn1, out_hc1, h1_ws);

    // 4) all 4 dec projections in one GEMM
    gemm(h1_ws, DD, wb_dec, DD, DD, nullptr, 0, nullptr, 0, 0,
         bias_dec, nullptr, decp_all, 2048, 2048, 0);

    // 5-7) p attention (32-row, r15 config) + fused a/i attention, then ONE combine
    {
        dim3 ag(B_DIM, 4);
        attn_fused<512><<<ag, 512, 0, stream>>>(p_enc, wb_p, decp_all, 2048, pv, Mv + 0, part_p, lsum_p);
        dim3 ag2(B_DIM, 4, 2);
        attn_fused_wreg2<<<ag2, 512, 0, stream>>>(
            a_enc, i_enc, wb_a, wb_i, decp_all + 512, decp_all + 1024, 2048,
            av, iv, Mv + 1, Mv + 2, part_a, part_i, lsum_a, lsum_i);
        dim3 cg(B_DIM, 4);
        ctx_combine3<<<cg, 256, 0, stream>>>(part_p, lsum_p, part_a, lsum_a, part_i, lsum_i,
                                             p_ctx, combined + (size_t)B_DIM * OD,
                                             combined + (size_t)2 * B_DIM * OD);
    }

    // 8) combined slot 0 = relu(p_ctx @ p2o_W^T + p2o_b)
    gemm(p_ctx, PD, wb_p2o, PD, PD, nullptr, 0, nullptr, 0, 0,
         p2o_b, nullptr, combined, OD, OD, 1);

    // 9) combiner attention over S'=3
    attn_score_mfma<256><<<(3 * B_DIM) / 64, 512, 0, stream>>>(
        combined, wb_c, decp_all + 1536, 2048, cv, score_c, 3);
    softmax_rows<<<B_DIM, 256, 0, stream>>>(score_c, 3);
    { dim3 cg(B_DIM, 1); ctx_kernel<<<cg, 256, 0, stream>>>(score_c, combined, ctx_c, 3, OD); }

    // 10) context = relu(ctx_c @ o2p_W^T + o2p_b)
    gemm(ctx_c, OD, wb_o2p, OD, OD, nullptr, 0, nullptr, 0, 0,
         o2p_b, nullptr, context, DD, DD, 1);

    // 11) h = relu([context, h1] @ out1_W^T + out1_b)
    gemm(context, DD, wb_out1, ID_DIM, DD,
         h1_ws, DD, wb_out1 + DD, ID_DIM, DD, out1_b, nullptr, h_big, ID_DIM, ID_DIM, 1);

    // 12) h2 = relu(h @ out2_W^T + out2_b)
    gemm(h_big, ID_DIM, wb_out2, ID_DIM, ID_DIM, nullptr, 0, nullptr, 0, 0,
         out2_b, nullptr, h2_buf, DD, DD, 1);

    // 13) ts
    ts_kernel<<<B_DIM, 64, 0, stream>>>(h2_buf, tg_W, tg_b, out_ts);

    // 14) cat = log_softmax(h2 @ mg_W^T + mg_b)
    gemm(h2_buf, DD, wb_mg, DD, DD, nullptr, 0, nullptr, 0, 0,
         mg_b, nullptr, logits, V_DIM, V_DIM, 0);
    log_softmax_rows<<<B_DIM, 256, 0, stream>>>(logits, out_cat, V_DIM);
}